// Round 14
// baseline (222.767 us; speedup 1.0000x reference)
//
#include <hip/hip_runtime.h>

static constexpr int NN = 50000;
static constexpr int NE = 800000;
static constexpr int NB = (NN + 255) / 256;   // 196
static constexpr int FB = (NE + 255) / 256;   // 3125 edge blocks
static constexpr int GG = ((NN + 15) / 16 + 3) / 4;  // 782 mgemm blocks (4 waves x 16 rows)
static constexpr int G128 = (NN * 8 + 255) / 256;    // 1563 gather<128> blocks (16 cols/thr)
static constexpr int G64  = (NN * 4 + 255) / 256;    // 782 gather<64> blocks
static constexpr int ZB = (NN * 8 * 8 / 16 + 255) / 256;  // 782 zero blocks
static constexpr float DSCALE = 33554432.f;   // 2^25 fixed-point for degree

typedef __attribute__((ext_vector_type(8))) short bf16x8;
typedef __attribute__((ext_vector_type(4))) float f32x4;

__device__ __forceinline__ unsigned short f2bf(float f) {  // RNE
  unsigned u = __float_as_uint(f);
  u += 0x7fffu + ((u >> 16) & 1u);
  return (unsigned short)(u >> 16);
}
__device__ __forceinline__ float bf_lo(unsigned v) { return __uint_as_float(v << 16); }
__device__ __forceinline__ float bf_hi(unsigned v) { return __uint_as_float(v & 0xffff0000u); }

__device__ __forceinline__ void bf8_unpack(uint4 v, float* f) {
  f[0] = bf_lo(v.x); f[1] = bf_hi(v.x); f[2] = bf_lo(v.y); f[3] = bf_hi(v.y);
  f[4] = bf_lo(v.z); f[5] = bf_hi(v.z); f[6] = bf_lo(v.w); f[7] = bf_hi(v.w);
}
__device__ __forceinline__ uint4 bf8_pack(const float* f) {
  uint4 o;
  o.x = (unsigned)f2bf(f[0]) | ((unsigned)f2bf(f[1]) << 16);
  o.y = (unsigned)f2bf(f[2]) | ((unsigned)f2bf(f[3]) << 16);
  o.z = (unsigned)f2bf(f[4]) | ((unsigned)f2bf(f[5]) << 16);
  o.w = (unsigned)f2bf(f[6]) | ((unsigned)f2bf(f[7]) << 16);
  return o;
}
__device__ __forceinline__ unsigned short f2h(float f) {
  _Float16 h = (_Float16)f;
  unsigned short u; __builtin_memcpy(&u, &h, 2);
  return u;
}
__device__ __forceinline__ float h2f(unsigned short u) {
  _Float16 h; __builtin_memcpy(&h, &u, 2);
  return (float)h;
}

// ---- zero the privatized histograms ----
__global__ __launch_bounds__(256) void k_zero(uint4* __restrict__ p) {
  int i = blockIdx.x * 256 + threadIdx.x;
  if (i < NN * 8 * 8 / 16) p[i] = make_uint4(0u, 0u, 0u, 0u);
}

// ---- B-fragment packing (16x16x32 MFMA B layout) ----
__device__ __forceinline__ void bfrag_item(const float* __restrict__ W,
                                           unsigned short* __restrict__ Bf,
                                           int K, int idx) {
  int fragc = (K / 32) * 4 * 64;
  int mat = idx / fragc;
  int rem = idx - mat * fragc;
  int lane = rem & 63;
  int nt = (rem >> 6) & 3;
  int kt = rem >> 8;
  int lrow = lane & 15, lgrp = lane >> 4;
  const float* Wm = W + (size_t)mat * K * 64;
  float o[8];
#pragma unroll
  for (int j = 0; j < 8; ++j)
    o[j] = Wm[(size_t)(kt * 32 + lgrp * 8 + j) * 64 + nt * 16 + lrow];
  *reinterpret_cast<uint4*>(Bf + (size_t)idx * 8) = bf8_pack(o);
}

// ---- mega-start: deg_hist | Wc | bc | BfW1 | cast x->xb  (grid-split) ----
__global__ __launch_bounds__(256) void k_start(const float* __restrict__ x,
                                               const float* __restrict__ W1,
                                               const float* __restrict__ W2,
                                               const float* __restrict__ Wlin,
                                               const float* __restrict__ b2,
                                               const float* __restrict__ bl,
                                               const int* __restrict__ col,
                                               const float* __restrict__ ew,
                                               unsigned long long* __restrict__ packed8,
                                               unsigned short* __restrict__ posarr,
                                               float* __restrict__ Wc,
                                               float* __restrict__ bc,
                                               unsigned short* __restrict__ BfW1,
                                               unsigned short* __restrict__ xb) {
  int b = blockIdx.x, t = threadIdx.x;
  if (b < FB) {  // per-edge histogram: copy = blockIdx&7; old low = position
    int e = b * 256 + t;
    if (e < NE) {
      unsigned fx = (unsigned)(ew[e] * DSCALE + 0.5f);
      int k = b & 7;
      unsigned long long old =
          atomicAdd(&packed8[(size_t)k * NN + col[e]], (((unsigned long long)fx) << 32) | 1ull);
      __builtin_nontemporal_store((unsigned short)(old & 0xffffull), posarr + e);
    }
    return;
  }
  b -= FB;
  if (b < 144) {  // Wc[p] = W2[p] @ Wl[64p:64p+64,:]
    int idx = b * 256 + t;
    int j = idx & 63;
    int k = (idx >> 6) % 192;
    int p = idx / (192 * 64);
    float s = 0.f;
    for (int m = 0; m < 64; ++m)
      s += W2[(p * 192 + k) * 64 + m] * Wlin[(p * 64 + m) * 64 + j];
    Wc[idx] = s;
    return;
  }
  b -= 144;
  if (b == 0) {  // bc
    if (t < 64) {
      float s = bl[t];
      for (int p = 0; p < 3; ++p)
        for (int m = 0; m < 64; ++m)
          s += b2[p * 64 + m] * Wlin[(p * 64 + m) * 64 + t];
      bc[t] = s;
    }
    return;
  }
  b -= 1;
  if (b < 9) {  // BfW1: 3 mats * 768 frags
    int idx = b * 256 + t;
    if (idx < 3 * 768) bfrag_item(W1, BfW1, 96, idx);
    return;
  }
  b -= 9;
  {  // cast x -> xb (float4 groups), non-temporal
    int i = b * 256 + t;
    if (i < NN * 24) {
      float4 v = reinterpret_cast<const float4*>(x)[i];
      unsigned lo = (unsigned)f2bf(v.x) | ((unsigned)f2bf(v.y) << 16);
      unsigned hi = (unsigned)f2bf(v.z) | ((unsigned)f2bf(v.w) << 16);
      unsigned long long pk = (unsigned long long)lo | ((unsigned long long)hi << 32);
      __builtin_nontemporal_store(pk, reinterpret_cast<unsigned long long*>(xb) + i);
    }
  }
}

// ---- scan part: sum 8 copies -> cnttot, dinv, per-copy offsets; block partial ----
__global__ __launch_bounds__(256) void k_scan_part(const unsigned long long* __restrict__ packed8,
                                                   int* __restrict__ partial,
                                                   float* __restrict__ dinv,
                                                   int* __restrict__ cnttot,
                                                   unsigned short* __restrict__ cumoff) {
  __shared__ int s[256];
  int t = threadIdx.x;
  int i = blockIdx.x * 256 + t;
  int total = 0;
  if (i < NN) {
    unsigned long long wsum = 0;
    int run = 0;
    unsigned short co[8];
#pragma unroll
    for (int k = 0; k < 8; ++k) {
      unsigned long long pk = packed8[(size_t)k * NN + i];
      co[k] = (unsigned short)run;
      run += (int)(pk & 0xffffffffu);
      wsum += (pk >> 32);
    }
    total = run;
    dinv[i] = rsqrtf(1.0f + (float)wsum * (1.0f / DSCALE));  // +1 self-loop
    cnttot[i] = total;
    uint4 pk4;
    pk4.x = (unsigned)co[0] | ((unsigned)co[1] << 16);
    pk4.y = (unsigned)co[2] | ((unsigned)co[3] << 16);
    pk4.z = (unsigned)co[4] | ((unsigned)co[5] << 16);
    pk4.w = (unsigned)co[6] | ((unsigned)co[7] << 16);
    reinterpret_cast<uint4*>(cumoff)[i] = pk4;
  }
  s[t] = total;
  __syncthreads();
  for (int off = 128; off > 0; off >>= 1) {
    if (t < off) s[t] += s[t + off];
    __syncthreads();
  }
  if (t == 0) partial[blockIdx.x] = s[0];
}

// ---- scan final ----
__global__ __launch_bounds__(256) void k_scan_final(const int* __restrict__ cnttot,
                                                    const int* __restrict__ partial,
                                                    int* __restrict__ rowptr) {
  __shared__ int s[256], p[256];
  int t = threadIdx.x;
  p[t] = (t < NB) ? partial[t] : 0;
  __syncthreads();
#pragma unroll
  for (int off = 1; off < 256; off <<= 1) {
    int a = (t >= off) ? p[t - off] : 0;
    __syncthreads();
    p[t] += a;
    __syncthreads();
  }
  int base = (blockIdx.x > 0) ? p[blockIdx.x - 1] : 0;
  int i = blockIdx.x * 256 + t;
  int v = (i < NN) ? cnttot[i] : 0;
  s[t] = v;
  __syncthreads();
#pragma unroll
  for (int off = 1; off < 256; off <<= 1) {
    int a = (t >= off) ? s[t - off] : 0;
    __syncthreads();
    s[t] += a;
    __syncthreads();
  }
  if (i < NN) rowptr[i] = s[t] - v + base;
  if (blockIdx.x == 0 && t == 0) rowptr[NN] = NE;
}

// ---- conv1 GEMM body (bf16 xb): c1_0=relu(x@W1_0+b1_0) | y=[x@W1_1 | x@W1_2] ----
__device__ __forceinline__ void mgemm_c1_body(int bid,
                                              const unsigned short* __restrict__ A,
                                              const unsigned short* __restrict__ BfW1,
                                              const float* __restrict__ b1,
                                              unsigned short* __restrict__ c1,
                                              unsigned short* __restrict__ y) {
  constexpr int KT = 3;
  int lane = threadIdx.x & 63;
  int wave = bid * 4 + (threadIdx.x >> 6);
  int r0 = wave * 16;
  if (r0 >= NN) return;
  int lrow = lane & 15, lgrp = lane >> 4;
  const unsigned short* ap = A + (size_t)(r0 + lrow) * 96 + lgrp * 8;
  const unsigned short* B0 = BfW1;
  const unsigned short* B1 = BfW1 + (size_t)768 * 8;
  const unsigned short* B2 = BfW1 + (size_t)2 * 768 * 8;
  f32x4 a0[4], a1[4], a2[4];
#pragma unroll
  for (int nt = 0; nt < 4; ++nt) {
    a0[nt] = (f32x4){0.f, 0.f, 0.f, 0.f};
    a1[nt] = (f32x4){0.f, 0.f, 0.f, 0.f};
    a2[nt] = (f32x4){0.f, 0.f, 0.f, 0.f};
  }
#pragma unroll
  for (int kt = 0; kt < KT; ++kt) {
    bf16x8 af = *reinterpret_cast<const bf16x8*>(ap + kt * 32);
#pragma unroll
    for (int nt = 0; nt < 4; ++nt) {
      size_t fo = (size_t)((kt * 4 + nt) * 64 + lane) * 8;
      bf16x8 b0 = *reinterpret_cast<const bf16x8*>(B0 + fo);
      bf16x8 b1f = *reinterpret_cast<const bf16x8*>(B1 + fo);
      bf16x8 b2f = *reinterpret_cast<const bf16x8*>(B2 + fo);
      a0[nt] = __builtin_amdgcn_mfma_f32_16x16x32_bf16(af, b0, a0[nt], 0, 0, 0);
      a1[nt] = __builtin_amdgcn_mfma_f32_16x16x32_bf16(af, b1f, a1[nt], 0, 0, 0);
      a2[nt] = __builtin_amdgcn_mfma_f32_16x16x32_bf16(af, b2f, a2[nt], 0, 0, 0);
    }
  }
#pragma unroll
  for (int nt = 0; nt < 4; ++nt) {
#pragma unroll
    for (int reg = 0; reg < 4; ++reg) {
      int rr = r0 + lgrp * 4 + reg;
      int cc = nt * 16 + lrow;
      c1[(size_t)rr * 192 + cc] = f2bf(fmaxf(a0[nt][reg] + b1[cc], 0.f));
      y[(size_t)rr * 128 + cc]      = f2bf(a1[nt][reg]);
      y[(size_t)rr * 128 + 64 + cc] = f2bf(a2[nt][reg]);
    }
  }
}

// ---- fill CSR (no atomics) + bfrag(Wc) + conv1 GEMM, grid-split ----
__global__ __launch_bounds__(256) void k_fill3(const int* __restrict__ row,
                                               const int* __restrict__ col,
                                               const float* __restrict__ w,
                                               const float* __restrict__ dinv,
                                               const int* __restrict__ rowptr,
                                               const unsigned short* __restrict__ posarr,
                                               const unsigned short* __restrict__ cumoff,
                                               unsigned* __restrict__ rec,
                                               const float* __restrict__ Wc,
                                               unsigned short* __restrict__ BfWc,
                                               const unsigned short* __restrict__ xb,
                                               const unsigned short* __restrict__ BfW1,
                                               const float* __restrict__ b1,
                                               unsigned short* __restrict__ c1,
                                               unsigned short* __restrict__ y) {
  int b = blockIdx.x;
  if (b < FB) {
    int e = b * 256 + threadIdx.x;
    if (e < NE) {
      int r = row[e], c = col[e];
      int k = b & 7;
      int pos = rowptr[c] + (int)cumoff[c * 8 + k] + (int)posarr[e];
      float nrm = dinv[r] * w[e] * dinv[c];
      rec[pos] = (unsigned)r | ((unsigned)f2h(nrm) << 16);
    }
    return;
  }
  b -= FB;
  if (b < 18) {
    int idx = b * 256 + threadIdx.x;
    if (idx < 3 * 1536) bfrag_item(Wc, BfWc, 192, idx);
    return;
  }
  mgemm_c1_body(b - 18, xb, BfW1, b1, c1, y);
}

// ---- propagate body: 32B chunks (16 cols/thread), bf16 h, fp32 accum, unroll-4.
// MODE 1: outb = bf16(add + prop)
// MODE 2: outf += prop
// MODE 3: F=128 split: cols 0-63 -> relu(+bias)->c1[64..127]; cols 64-127 -> outb (q2)
// MODE 4: F=64: relu(+bias) -> c1[128..191]
template<int F, int MODE>
__device__ __forceinline__ void gather_body(int bid,
                                            const unsigned short* __restrict__ h,
                                            const float* __restrict__ dinv,
                                            const int* __restrict__ rowptr,
                                            const unsigned* __restrict__ rec,
                                            const unsigned short* __restrict__ add,
                                            unsigned short* __restrict__ outb,
                                            float* __restrict__ outf,
                                            const float* __restrict__ bias,
                                            unsigned short* __restrict__ c1) {
  constexpr int CH = F / 16;
  int idx = bid * 256 + threadIdx.x;
  if (idx >= NN * CH) return;
  int node = idx / CH;
  int col = (idx - node * CH) * 16;
  const size_t base = (size_t)node * F + col;
  float a[16];
  {
    uint4 h0 = *reinterpret_cast<const uint4*>(h + base);
    uint4 h1 = *reinterpret_cast<const uint4*>(h + base + 8);
    bf8_unpack(h0, a); bf8_unpack(h1, a + 8);
    float d2 = dinv[node]; d2 *= d2;
#pragma unroll
    for (int j = 0; j < 16; ++j) a[j] *= d2;
  }
  if (MODE == 1) {
    uint4 a0 = *reinterpret_cast<const uint4*>(add + base);
    uint4 a1 = *reinterpret_cast<const uint4*>(add + base + 8);
    float ax[16]; bf8_unpack(a0, ax); bf8_unpack(a1, ax + 8);
#pragma unroll
    for (int j = 0; j < 16; ++j) a[j] += ax[j];
  } else if (MODE == 2) {
#pragma unroll
    for (int q = 0; q < 4; ++q) {
      float4 ov = *reinterpret_cast<const float4*>(outf + base + q * 4);
      a[q * 4 + 0] += ov.x; a[q * 4 + 1] += ov.y;
      a[q * 4 + 2] += ov.z; a[q * 4 + 3] += ov.w;
    }
  }
  int e = rowptr[node], e1 = rowptr[node + 1];
  for (; e + 4 <= e1; e += 4) {
    unsigned rv0 = rec[e], rv1 = rec[e + 1], rv2 = rec[e + 2], rv3 = rec[e + 3];
    const unsigned short* p0 = h + (size_t)(rv0 & 0xffffu) * F + col;
    const unsigned short* p1 = h + (size_t)(rv1 & 0xffffu) * F + col;
    const unsigned short* p2 = h + (size_t)(rv2 & 0xffffu) * F + col;
    const unsigned short* p3 = h + (size_t)(rv3 & 0xffffu) * F + col;
    uint4 s00 = *reinterpret_cast<const uint4*>(p0);
    uint4 s01 = *reinterpret_cast<const uint4*>(p0 + 8);
    uint4 s10 = *reinterpret_cast<const uint4*>(p1);
    uint4 s11 = *reinterpret_cast<const uint4*>(p1 + 8);
    uint4 s20 = *reinterpret_cast<const uint4*>(p2);
    uint4 s21 = *reinterpret_cast<const uint4*>(p2 + 8);
    uint4 s30 = *reinterpret_cast<const uint4*>(p3);
    uint4 s31 = *reinterpret_cast<const uint4*>(p3 + 8);
    float nm0 = h2f((unsigned short)(rv0 >> 16));
    float nm1 = h2f((unsigned short)(rv1 >> 16));
    float nm2 = h2f((unsigned short)(rv2 >> 16));
    float nm3 = h2f((unsigned short)(rv3 >> 16));
    float sx[16];
    bf8_unpack(s00, sx); bf8_unpack(s01, sx + 8);
#pragma unroll
    for (int j = 0; j < 16; ++j) a[j] += nm0 * sx[j];
    bf8_unpack(s10, sx); bf8_unpack(s11, sx + 8);
#pragma unroll
    for (int j = 0; j < 16; ++j) a[j] += nm1 * sx[j];
    bf8_unpack(s20, sx); bf8_unpack(s21, sx + 8);
#pragma unroll
    for (int j = 0; j < 16; ++j) a[j] += nm2 * sx[j];
    bf8_unpack(s30, sx); bf8_unpack(s31, sx + 8);
#pragma unroll
    for (int j = 0; j < 16; ++j) a[j] += nm3 * sx[j];
  }
  for (; e < e1; ++e) {
    unsigned rv = rec[e];
    const unsigned short* p0 = h + (size_t)(rv & 0xffffu) * F + col;
    uint4 s0 = *reinterpret_cast<const uint4*>(p0);
    uint4 s1 = *reinterpret_cast<const uint4*>(p0 + 8);
    float nm = h2f((unsigned short)(rv >> 16));
    float sx[16]; bf8_unpack(s0, sx); bf8_unpack(s1, sx + 8);
#pragma unroll
    for (int j = 0; j < 16; ++j) a[j] += nm * sx[j];
  }
  if (MODE == 1) {
    *reinterpret_cast<uint4*>(outb + base) = bf8_pack(a);
    *reinterpret_cast<uint4*>(outb + base + 8) = bf8_pack(a + 8);
  } else if (MODE == 2) {
#pragma unroll
    for (int q = 0; q < 4; ++q)
      *reinterpret_cast<float4*>(outf + base + q * 4) =
          make_float4(a[q * 4], a[q * 4 + 1], a[q * 4 + 2], a[q * 4 + 3]);
  } else if (MODE == 3) {
    if (col < 64) {
#pragma unroll
      for (int j = 0; j < 16; ++j) a[j] = fmaxf(a[j] + bias[col + j], 0.f);
      unsigned short* cp = c1 + (size_t)node * 192 + 64 + col;
      *reinterpret_cast<uint4*>(cp) = bf8_pack(a);
      *reinterpret_cast<uint4*>(cp + 8) = bf8_pack(a + 8);
    } else {
      unsigned short* qp = outb + (size_t)node * 64 + (col - 64);
      *reinterpret_cast<uint4*>(qp) = bf8_pack(a);
      *reinterpret_cast<uint4*>(qp + 8) = bf8_pack(a + 8);
    }
  } else {  // MODE 4
#pragma unroll
    for (int j = 0; j < 16; ++j) a[j] = fmaxf(a[j] + bias[col + j], 0.f);
    unsigned short* cp = c1 + (size_t)node * 192 + 128 + col;
    *reinterpret_cast<uint4*>(cp) = bf8_pack(a);
    *reinterpret_cast<uint4*>(cp + 8) = bf8_pack(a + 8);
  }
}

template<int F, int MODE>
__global__ __launch_bounds__(256) void k_gather(const unsigned short* __restrict__ h,
                                                const float* __restrict__ dinv,
                                                const int* __restrict__ rowptr,
                                                const unsigned* __restrict__ rec,
                                                const unsigned short* __restrict__ add,
                                                unsigned short* __restrict__ outb,
                                                float* __restrict__ outf,
                                                const float* __restrict__ bias,
                                                unsigned short* __restrict__ c1) {
  gather_body<F, MODE>(blockIdx.x, h, dinv, rowptr, rec, add, outb, outf, bias, c1);
}

// ---- triple K=192 GEMM sharing A=c1: out(fp32,+bc) | z1(bf16) | z2(bf16) ----
__global__ __launch_bounds__(256) void k_mgemm3(const unsigned short* __restrict__ A,
                                                const unsigned short* __restrict__ BfWc,
                                                const float* __restrict__ bc,
                                                float* __restrict__ out,
                                                unsigned short* __restrict__ z1,
                                                unsigned short* __restrict__ z2) {
  constexpr int KT = 6;
  int lane = threadIdx.x & 63;
  int wave = blockIdx.x * 4 + (threadIdx.x >> 6);
  int r0 = wave * 16;
  if (r0 >= NN) return;
  int lrow = lane & 15, lgrp = lane >> 4;
  const unsigned short* ap = A + (size_t)(r0 + lrow) * 192 + lgrp * 8;
  const unsigned short* B0 = BfWc;
  const unsigned short* B1 = BfWc + (size_t)1536 * 8;
  const unsigned short* B2 = BfWc + (size_t)2 * 1536 * 8;
  f32x4 a0[4], a1[4], a2[4];
#pragma unroll
  for (int nt = 0; nt < 4; ++nt) {
    a0[nt] = (f32x4){0.f, 0.f, 0.f, 0.f};
    a1[nt] = (f32x4){0.f, 0.f, 0.f, 0.f};
    a2[nt] = (f32x4){0.f, 0.f, 0.f, 0.f};
  }
#pragma unroll
  for (int kt = 0; kt < KT; ++kt) {
    bf16x8 af = *reinterpret_cast<const bf16x8*>(ap + kt * 32);
#pragma unroll
    for (int nt = 0; nt < 4; ++nt) {
      size_t fo = (size_t)((kt * 4 + nt) * 64 + lane) * 8;
      bf16x8 b0 = *reinterpret_cast<const bf16x8*>(B0 + fo);
      bf16x8 b1 = *reinterpret_cast<const bf16x8*>(B1 + fo);
      bf16x8 b2 = *reinterpret_cast<const bf16x8*>(B2 + fo);
      a0[nt] = __builtin_amdgcn_mfma_f32_16x16x32_bf16(af, b0, a0[nt], 0, 0, 0);
      a1[nt] = __builtin_amdgcn_mfma_f32_16x16x32_bf16(af, b1, a1[nt], 0, 0, 0);
      a2[nt] = __builtin_amdgcn_mfma_f32_16x16x32_bf16(af, b2, a2[nt], 0, 0, 0);
    }
  }
#pragma unroll
  for (int nt = 0; nt < 4; ++nt) {
#pragma unroll
    for (int reg = 0; reg < 4; ++reg) {
      int rr = r0 + lgrp * 4 + reg;
      int cc = nt * 16 + lrow;
      out[(size_t)rr * 64 + cc] = a0[nt][reg] + bc[cc];
      z1[(size_t)rr * 64 + cc] = f2bf(a1[nt][reg]);
      z2[(size_t)rr * 64 + cc] = f2bf(a2[nt][reg]);
    }
  }
}

extern "C" void kernel_launch(void* const* d_in, const int* in_sizes, int n_in,
                              void* d_out, int out_size, void* d_ws, size_t ws_size,
                              hipStream_t stream) {
  const float* x    = (const float*)d_in[0];
  const int*   ei   = (const int*)d_in[1];
  const float* ew   = (const float*)d_in[2];
  const float* W1   = (const float*)d_in[3];
  const float* b1   = (const float*)d_in[4];
  const float* W2   = (const float*)d_in[5];
  const float* b2   = (const float*)d_in[6];
  const float* Wlin = (const float*)d_in[7];
  const float* bl   = (const float*)d_in[8];
  float* out = (float*)d_out;

  const int* row = ei;
  const int* col = ei + NE;

  char* wsb = (char*)d_ws;
  unsigned long long* packed8 = (unsigned long long*)wsb; wsb += (size_t)8 * NN * 8;
  float* dinv    = (float*)wsb;  wsb += NN * 4;
  int*   cnttot  = (int*)wsb;    wsb += NN * 4;
  int*   rowptr  = (int*)wsb;    wsb += (NN + 1) * 4;
  int*   partial = (int*)wsb;    wsb += 256 * 4;
  wsb = (char*)(((size_t)wsb + 15) & ~(size_t)15);
  unsigned short* cumoff = (unsigned short*)wsb; wsb += (size_t)NN * 8 * 2;
  unsigned short* posarr = (unsigned short*)wsb; wsb += NE * 2;
  wsb = (char*)(((size_t)wsb + 15) & ~(size_t)15);
  unsigned* rec  = (unsigned*)wsb; wsb += (size_t)NE * 4;
  float* Wc      = (float*)wsb;  wsb += 3 * 192 * 64 * 4;
  float* bc      = (float*)wsb;  wsb += 64 * 4;
  wsb = (char*)(((size_t)wsb + 15) & ~(size_t)15);
  unsigned short* BfW1 = (unsigned short*)wsb; wsb += (size_t)3 * 768 * 8 * 2;
  unsigned short* BfWc = (unsigned short*)wsb; wsb += (size_t)3 * 1536 * 8 * 2;
  wsb = (char*)(((size_t)wsb + 15) & ~(size_t)15);
  unsigned short* xb   = (unsigned short*)wsb; wsb += (size_t)NN * 96 * 2;
  unsigned short* c1   = (unsigned short*)wsb; wsb += (size_t)NN * 192 * 2;
  unsigned short* bufB = (unsigned short*)wsb;  // y(128)|q2(64), then z1|z2|sB (3*64)
  unsigned short* y  = bufB;
  unsigned short* q2 = bufB + (size_t)NN * 128;
  unsigned short* z1 = bufB;
  unsigned short* z2 = bufB + (size_t)NN * 64;
  unsigned short* sB = bufB + (size_t)NN * 128;

  // zero privatized histograms
  k_zero<<<ZB, 256, 0, stream>>>((uint4*)packed8);
  // mega-start: histogram atomics + weight prep + cast, one launch
  const int CASTB = (NN * 24 + 255) / 256;
  k_start<<<FB + 144 + 1 + 9 + CASTB, 256, 0, stream>>>(x, W1, W2, Wlin, b2, bl,
                                                        col, ew, packed8, posarr,
                                                        Wc, bc, BfW1, xb);
  // dinv + rowptr
  k_scan_part<<<NB, 256, 0, stream>>>(packed8, partial, dinv, cnttot, cumoff);
  k_scan_final<<<NB, 256, 0, stream>>>(cnttot, partial, rowptr);
  // CSR fill + BfWc pack + conv1 GEMM (bf16 xb -> c1_0, y), co-launched
  k_fill3<<<FB + 18 + GG, 256, 0, stream>>>(row, col, ew, dinv, rowptr, posarr, cumoff,
                                            rec, Wc, BfWc, xb, BfW1, b1, c1, y);

  // conv1 propagation: q = A y -> c1_1 (bias+relu) | q2; t = A q2 -> c1_2
  k_gather<128, 3><<<G128, 256, 0, stream>>>(y, dinv, rowptr, rec, nullptr, q2, nullptr,
                                             b1 + 64, c1);
  k_gather<64, 4><<<G64, 256, 0, stream>>>(q2, dinv, rowptr, rec, nullptr, nullptr, nullptr,
                                           b1 + 128, c1);

  // conv2 + final linear (re-associated): out = c1@Wc0 + bc + A(z1 + A z2)
  k_mgemm3<<<GG, 256, 0, stream>>>(c1, BfWc, bc, out, z1, z2);
  k_gather<64, 1><<<G64, 256, 0, stream>>>(z2, dinv, rowptr, rec, z1, sB, nullptr,
                                           nullptr, nullptr);
  k_gather<64, 2><<<G64, 256, 0, stream>>>(sB, dinv, rowptr, rec, nullptr, nullptr, out,
                                           nullptr, nullptr);
}

// Round 15
// 213.149 us; speedup vs baseline: 1.0451x; 1.0451x over previous
//
#include <hip/hip_runtime.h>

static constexpr int NN = 50000;
static constexpr int NE = 800000;
static constexpr int NB = (NN + 255) / 256;   // 196
static constexpr int FB = (NE + 255) / 256;   // 3125 edge blocks
static constexpr int GG = ((NN + 15) / 16 + 3) / 4;  // 782 mgemm blocks (4 waves x 16 rows)
static constexpr int G128 = (NN * 16 + 255) / 256;   // 3125 gather<128> blocks (8 cols/thr)
static constexpr int G64  = (NN * 8 + 255) / 256;    // 1563 gather<64> blocks
static constexpr int ZB = (NN * 8 * 8 / 16 + 255) / 256;  // 782 zero blocks
static constexpr float DSCALE = 33554432.f;   // 2^25 fixed-point for degree

typedef __attribute__((ext_vector_type(8))) short bf16x8;
typedef __attribute__((ext_vector_type(4))) float f32x4;

__device__ __forceinline__ unsigned short f2bf(float f) {  // RNE
  unsigned u = __float_as_uint(f);
  u += 0x7fffu + ((u >> 16) & 1u);
  return (unsigned short)(u >> 16);
}
__device__ __forceinline__ float bf_lo(unsigned v) { return __uint_as_float(v << 16); }
__device__ __forceinline__ float bf_hi(unsigned v) { return __uint_as_float(v & 0xffff0000u); }

__device__ __forceinline__ void bf8_unpack(uint4 v, float* f) {
  f[0] = bf_lo(v.x); f[1] = bf_hi(v.x); f[2] = bf_lo(v.y); f[3] = bf_hi(v.y);
  f[4] = bf_lo(v.z); f[5] = bf_hi(v.z); f[6] = bf_lo(v.w); f[7] = bf_hi(v.w);
}
__device__ __forceinline__ uint4 bf8_pack(const float* f) {
  uint4 o;
  o.x = (unsigned)f2bf(f[0]) | ((unsigned)f2bf(f[1]) << 16);
  o.y = (unsigned)f2bf(f[2]) | ((unsigned)f2bf(f[3]) << 16);
  o.z = (unsigned)f2bf(f[4]) | ((unsigned)f2bf(f[5]) << 16);
  o.w = (unsigned)f2bf(f[6]) | ((unsigned)f2bf(f[7]) << 16);
  return o;
}
__device__ __forceinline__ unsigned short f2h(float f) {
  _Float16 h = (_Float16)f;
  unsigned short u; __builtin_memcpy(&u, &h, 2);
  return u;
}
__device__ __forceinline__ float h2f(unsigned short u) {
  _Float16 h; __builtin_memcpy(&h, &u, 2);
  return (float)h;
}

// ---- zero the privatized histograms ----
__global__ __launch_bounds__(256) void k_zero(uint4* __restrict__ p) {
  int i = blockIdx.x * 256 + threadIdx.x;
  if (i < NN * 8 * 8 / 16) p[i] = make_uint4(0u, 0u, 0u, 0u);
}

// ---- B-fragment packing (16x16x32 MFMA B layout) ----
__device__ __forceinline__ void bfrag_item(const float* __restrict__ W,
                                           unsigned short* __restrict__ Bf,
                                           int K, int idx) {
  int fragc = (K / 32) * 4 * 64;
  int mat = idx / fragc;
  int rem = idx - mat * fragc;
  int lane = rem & 63;
  int nt = (rem >> 6) & 3;
  int kt = rem >> 8;
  int lrow = lane & 15, lgrp = lane >> 4;
  const float* Wm = W + (size_t)mat * K * 64;
  float o[8];
#pragma unroll
  for (int j = 0; j < 8; ++j)
    o[j] = Wm[(size_t)(kt * 32 + lgrp * 8 + j) * 64 + nt * 16 + lrow];
  *reinterpret_cast<uint4*>(Bf + (size_t)idx * 8) = bf8_pack(o);
}

// ---- mega-start: deg_hist | Wc | bc | BfW1 | cast x->xb  (grid-split) ----
__global__ __launch_bounds__(256) void k_start(const float* __restrict__ x,
                                               const float* __restrict__ W1,
                                               const float* __restrict__ W2,
                                               const float* __restrict__ Wlin,
                                               const float* __restrict__ b2,
                                               const float* __restrict__ bl,
                                               const int* __restrict__ col,
                                               const float* __restrict__ ew,
                                               unsigned long long* __restrict__ packed8,
                                               unsigned short* __restrict__ posarr,
                                               float* __restrict__ Wc,
                                               float* __restrict__ bc,
                                               unsigned short* __restrict__ BfW1,
                                               unsigned short* __restrict__ xb) {
  int b = blockIdx.x, t = threadIdx.x;
  if (b < FB) {  // per-edge histogram: copy = blockIdx&7; old low = position
    int e = b * 256 + t;
    if (e < NE) {
      unsigned fx = (unsigned)(ew[e] * DSCALE + 0.5f);
      int k = b & 7;
      unsigned long long old =
          atomicAdd(&packed8[(size_t)k * NN + col[e]], (((unsigned long long)fx) << 32) | 1ull);
      __builtin_nontemporal_store((unsigned short)(old & 0xffffull), posarr + e);
    }
    return;
  }
  b -= FB;
  if (b < 144) {  // Wc[p] = W2[p] @ Wl[64p:64p+64,:]
    int idx = b * 256 + t;
    int j = idx & 63;
    int k = (idx >> 6) % 192;
    int p = idx / (192 * 64);
    float s = 0.f;
    for (int m = 0; m < 64; ++m)
      s += W2[(p * 192 + k) * 64 + m] * Wlin[(p * 64 + m) * 64 + j];
    Wc[idx] = s;
    return;
  }
  b -= 144;
  if (b == 0) {  // bc
    if (t < 64) {
      float s = bl[t];
      for (int p = 0; p < 3; ++p)
        for (int m = 0; m < 64; ++m)
          s += b2[p * 64 + m] * Wlin[(p * 64 + m) * 64 + t];
      bc[t] = s;
    }
    return;
  }
  b -= 1;
  if (b < 9) {  // BfW1: 3 mats * 768 frags
    int idx = b * 256 + t;
    if (idx < 3 * 768) bfrag_item(W1, BfW1, 96, idx);
    return;
  }
  b -= 9;
  {  // cast x -> xb (float4 groups), non-temporal
    int i = b * 256 + t;
    if (i < NN * 24) {
      float4 v = reinterpret_cast<const float4*>(x)[i];
      unsigned lo = (unsigned)f2bf(v.x) | ((unsigned)f2bf(v.y) << 16);
      unsigned hi = (unsigned)f2bf(v.z) | ((unsigned)f2bf(v.w) << 16);
      unsigned long long pk = (unsigned long long)lo | ((unsigned long long)hi << 32);
      __builtin_nontemporal_store(pk, reinterpret_cast<unsigned long long*>(xb) + i);
    }
  }
}

// ---- scan part: sum 8 copies -> cnttot, dinv, per-copy offsets; block partial ----
__global__ __launch_bounds__(256) void k_scan_part(const unsigned long long* __restrict__ packed8,
                                                   int* __restrict__ partial,
                                                   float* __restrict__ dinv,
                                                   int* __restrict__ cnttot,
                                                   unsigned short* __restrict__ cumoff) {
  __shared__ int s[256];
  int t = threadIdx.x;
  int i = blockIdx.x * 256 + t;
  int total = 0;
  if (i < NN) {
    unsigned long long wsum = 0;
    int run = 0;
    unsigned short co[8];
#pragma unroll
    for (int k = 0; k < 8; ++k) {
      unsigned long long pk = packed8[(size_t)k * NN + i];
      co[k] = (unsigned short)run;
      run += (int)(pk & 0xffffffffu);
      wsum += (pk >> 32);
    }
    total = run;
    dinv[i] = rsqrtf(1.0f + (float)wsum * (1.0f / DSCALE));  // +1 self-loop
    cnttot[i] = total;
    uint4 pk4;
    pk4.x = (unsigned)co[0] | ((unsigned)co[1] << 16);
    pk4.y = (unsigned)co[2] | ((unsigned)co[3] << 16);
    pk4.z = (unsigned)co[4] | ((unsigned)co[5] << 16);
    pk4.w = (unsigned)co[6] | ((unsigned)co[7] << 16);
    reinterpret_cast<uint4*>(cumoff)[i] = pk4;
  }
  s[t] = total;
  __syncthreads();
  for (int off = 128; off > 0; off >>= 1) {
    if (t < off) s[t] += s[t + off];
    __syncthreads();
  }
  if (t == 0) partial[blockIdx.x] = s[0];
}

// ---- scan final ----
__global__ __launch_bounds__(256) void k_scan_final(const int* __restrict__ cnttot,
                                                    const int* __restrict__ partial,
                                                    int* __restrict__ rowptr) {
  __shared__ int s[256], p[256];
  int t = threadIdx.x;
  p[t] = (t < NB) ? partial[t] : 0;
  __syncthreads();
#pragma unroll
  for (int off = 1; off < 256; off <<= 1) {
    int a = (t >= off) ? p[t - off] : 0;
    __syncthreads();
    p[t] += a;
    __syncthreads();
  }
  int base = (blockIdx.x > 0) ? p[blockIdx.x - 1] : 0;
  int i = blockIdx.x * 256 + t;
  int v = (i < NN) ? cnttot[i] : 0;
  s[t] = v;
  __syncthreads();
#pragma unroll
  for (int off = 1; off < 256; off <<= 1) {
    int a = (t >= off) ? s[t - off] : 0;
    __syncthreads();
    s[t] += a;
    __syncthreads();
  }
  if (i < NN) rowptr[i] = s[t] - v + base;
  if (blockIdx.x == 0 && t == 0) rowptr[NN] = NE;
}

// ---- conv1 GEMM body: K=96, 3 mats: c1_0=relu(x@W1_0+b1_0) | y=[x@W1_1 | x@W1_2] ----
__device__ __forceinline__ void mgemm_c1_body(int bid,
                                              const unsigned short* __restrict__ A,
                                              const unsigned short* __restrict__ BfW1,
                                              const float* __restrict__ b1,
                                              unsigned short* __restrict__ c1,
                                              unsigned short* __restrict__ y) {
  constexpr int KT = 3;
  int lane = threadIdx.x & 63;
  int wave = bid * 4 + (threadIdx.x >> 6);
  int r0 = wave * 16;
  if (r0 >= NN) return;
  int lrow = lane & 15, lgrp = lane >> 4;
  const unsigned short* ap = A + (size_t)(r0 + lrow) * 96 + lgrp * 8;
  const unsigned short* B0 = BfW1;
  const unsigned short* B1 = BfW1 + (size_t)768 * 8;
  const unsigned short* B2 = BfW1 + (size_t)2 * 768 * 8;
  f32x4 a0[4], a1[4], a2[4];
#pragma unroll
  for (int nt = 0; nt < 4; ++nt) {
    a0[nt] = (f32x4){0.f, 0.f, 0.f, 0.f};
    a1[nt] = (f32x4){0.f, 0.f, 0.f, 0.f};
    a2[nt] = (f32x4){0.f, 0.f, 0.f, 0.f};
  }
#pragma unroll
  for (int kt = 0; kt < KT; ++kt) {
    bf16x8 af = *reinterpret_cast<const bf16x8*>(ap + kt * 32);
#pragma unroll
    for (int nt = 0; nt < 4; ++nt) {
      size_t fo = (size_t)((kt * 4 + nt) * 64 + lane) * 8;
      bf16x8 b0 = *reinterpret_cast<const bf16x8*>(B0 + fo);
      bf16x8 b1f = *reinterpret_cast<const bf16x8*>(B1 + fo);
      bf16x8 b2f = *reinterpret_cast<const bf16x8*>(B2 + fo);
      a0[nt] = __builtin_amdgcn_mfma_f32_16x16x32_bf16(af, b0, a0[nt], 0, 0, 0);
      a1[nt] = __builtin_amdgcn_mfma_f32_16x16x32_bf16(af, b1f, a1[nt], 0, 0, 0);
      a2[nt] = __builtin_amdgcn_mfma_f32_16x16x32_bf16(af, b2f, a2[nt], 0, 0, 0);
    }
  }
#pragma unroll
  for (int nt = 0; nt < 4; ++nt) {
#pragma unroll
    for (int reg = 0; reg < 4; ++reg) {
      int rr = r0 + lgrp * 4 + reg;
      int cc = nt * 16 + lrow;
      c1[(size_t)rr * 192 + cc] = f2bf(fmaxf(a0[nt][reg] + b1[cc], 0.f));
      y[(size_t)rr * 128 + cc]      = f2bf(a1[nt][reg]);
      y[(size_t)rr * 128 + 64 + cc] = f2bf(a2[nt][reg]);
    }
  }
}

// ---- fill CSR (no atomics) + bfrag(Wc) + conv1 GEMM, grid-split ----
__global__ __launch_bounds__(256) void k_fill3(const int* __restrict__ row,
                                               const int* __restrict__ col,
                                               const float* __restrict__ w,
                                               const float* __restrict__ dinv,
                                               const int* __restrict__ rowptr,
                                               const unsigned short* __restrict__ posarr,
                                               const unsigned short* __restrict__ cumoff,
                                               unsigned* __restrict__ rec,
                                               const float* __restrict__ Wc,
                                               unsigned short* __restrict__ BfWc,
                                               const unsigned short* __restrict__ xb,
                                               const unsigned short* __restrict__ BfW1,
                                               const float* __restrict__ b1,
                                               unsigned short* __restrict__ c1,
                                               unsigned short* __restrict__ y) {
  int b = blockIdx.x;
  if (b < FB) {
    int e = b * 256 + threadIdx.x;
    if (e < NE) {
      int r = row[e], c = col[e];
      int k = b & 7;
      int pos = rowptr[c] + (int)cumoff[c * 8 + k] + (int)posarr[e];
      float nrm = dinv[r] * w[e] * dinv[c];
      rec[pos] = (unsigned)r | ((unsigned)f2h(nrm) << 16);
    }
    return;
  }
  b -= FB;
  if (b < 18) {
    int idx = b * 256 + threadIdx.x;
    if (idx < 3 * 1536) bfrag_item(Wc, BfWc, 192, idx);
    return;
  }
  mgemm_c1_body(b - 18, xb, BfW1, b1, c1, y);
}

// ---- propagate body (bf16 h, fp32 accum, fp16 nrm, unroll-4, 16B chunks).
// MODE 1: outb = bf16(add + prop)
// MODE 2: outf += prop
// MODE 3: F=128 split: cols 0-63 -> relu(+bias)->c1[64..127]; cols 64-127 -> outb (q2)
// MODE 4: F=64: relu(+bias) -> c1[128..191]
template<int F, int MODE>
__device__ __forceinline__ void gather_body(int bid,
                                            const unsigned short* __restrict__ h,
                                            const float* __restrict__ dinv,
                                            const int* __restrict__ rowptr,
                                            const unsigned* __restrict__ rec,
                                            const unsigned short* __restrict__ add,
                                            unsigned short* __restrict__ outb,
                                            float* __restrict__ outf,
                                            const float* __restrict__ bias,
                                            unsigned short* __restrict__ c1) {
  constexpr int CH = F / 8;
  int idx = bid * 256 + threadIdx.x;
  if (idx >= NN * CH) return;
  int node = idx / CH;
  int col = (idx - node * CH) * 8;
  const size_t base = (size_t)node * F + col;
  uint4 hv = *reinterpret_cast<const uint4*>(h + base);
  float hx[8]; bf8_unpack(hv, hx);
  float d2 = dinv[node]; d2 *= d2;
  float a[8];
#pragma unroll
  for (int j = 0; j < 8; ++j) a[j] = d2 * hx[j];
  if (MODE == 1) {
    uint4 av = *reinterpret_cast<const uint4*>(add + base);
    float ax[8]; bf8_unpack(av, ax);
#pragma unroll
    for (int j = 0; j < 8; ++j) a[j] += ax[j];
  } else if (MODE == 2) {
    float4 o0 = *reinterpret_cast<const float4*>(outf + base);
    float4 o1 = *reinterpret_cast<const float4*>(outf + base + 4);
    a[0] += o0.x; a[1] += o0.y; a[2] += o0.z; a[3] += o0.w;
    a[4] += o1.x; a[5] += o1.y; a[6] += o1.z; a[7] += o1.w;
  }
  int e = rowptr[node], e1 = rowptr[node + 1];
  for (; e + 4 <= e1; e += 4) {
    unsigned rv0 = rec[e], rv1 = rec[e + 1], rv2 = rec[e + 2], rv3 = rec[e + 3];
    uint4 s0 = *reinterpret_cast<const uint4*>(h + (size_t)(rv0 & 0xffffu) * F + col);
    uint4 s1 = *reinterpret_cast<const uint4*>(h + (size_t)(rv1 & 0xffffu) * F + col);
    uint4 s2 = *reinterpret_cast<const uint4*>(h + (size_t)(rv2 & 0xffffu) * F + col);
    uint4 s3 = *reinterpret_cast<const uint4*>(h + (size_t)(rv3 & 0xffffu) * F + col);
    float nm0 = h2f((unsigned short)(rv0 >> 16));
    float nm1 = h2f((unsigned short)(rv1 >> 16));
    float nm2 = h2f((unsigned short)(rv2 >> 16));
    float nm3 = h2f((unsigned short)(rv3 >> 16));
    float sx[8];
    bf8_unpack(s0, sx);
#pragma unroll
    for (int j = 0; j < 8; ++j) a[j] += nm0 * sx[j];
    bf8_unpack(s1, sx);
#pragma unroll
    for (int j = 0; j < 8; ++j) a[j] += nm1 * sx[j];
    bf8_unpack(s2, sx);
#pragma unroll
    for (int j = 0; j < 8; ++j) a[j] += nm2 * sx[j];
    bf8_unpack(s3, sx);
#pragma unroll
    for (int j = 0; j < 8; ++j) a[j] += nm3 * sx[j];
  }
  for (; e < e1; ++e) {
    unsigned rv = rec[e];
    uint4 sv = *reinterpret_cast<const uint4*>(h + (size_t)(rv & 0xffffu) * F + col);
    float nm = h2f((unsigned short)(rv >> 16));
    float sx[8]; bf8_unpack(sv, sx);
#pragma unroll
    for (int j = 0; j < 8; ++j) a[j] += nm * sx[j];
  }
  if (MODE == 1) {
    *reinterpret_cast<uint4*>(outb + base) = bf8_pack(a);
  } else if (MODE == 2) {
    *reinterpret_cast<float4*>(outf + base) = make_float4(a[0], a[1], a[2], a[3]);
    *reinterpret_cast<float4*>(outf + base + 4) = make_float4(a[4], a[5], a[6], a[7]);
  } else if (MODE == 3) {
    if (col < 64) {
      float4 b0 = *reinterpret_cast<const float4*>(bias + col);
      float4 b1v = *reinterpret_cast<const float4*>(bias + col + 4);
      a[0] = fmaxf(a[0] + b0.x, 0.f); a[1] = fmaxf(a[1] + b0.y, 0.f);
      a[2] = fmaxf(a[2] + b0.z, 0.f); a[3] = fmaxf(a[3] + b0.w, 0.f);
      a[4] = fmaxf(a[4] + b1v.x, 0.f); a[5] = fmaxf(a[5] + b1v.y, 0.f);
      a[6] = fmaxf(a[6] + b1v.z, 0.f); a[7] = fmaxf(a[7] + b1v.w, 0.f);
      *reinterpret_cast<uint4*>(c1 + (size_t)node * 192 + 64 + col) = bf8_pack(a);
    } else {
      *reinterpret_cast<uint4*>(outb + (size_t)node * 64 + (col - 64)) = bf8_pack(a);
    }
  } else {  // MODE 4
    float4 b0 = *reinterpret_cast<const float4*>(bias + col);
    float4 b1v = *reinterpret_cast<const float4*>(bias + col + 4);
    a[0] = fmaxf(a[0] + b0.x, 0.f); a[1] = fmaxf(a[1] + b0.y, 0.f);
    a[2] = fmaxf(a[2] + b0.z, 0.f); a[3] = fmaxf(a[3] + b0.w, 0.f);
    a[4] = fmaxf(a[4] + b1v.x, 0.f); a[5] = fmaxf(a[5] + b1v.y, 0.f);
    a[6] = fmaxf(a[6] + b1v.z, 0.f); a[7] = fmaxf(a[7] + b1v.w, 0.f);
    *reinterpret_cast<uint4*>(c1 + (size_t)node * 192 + 128 + col) = bf8_pack(a);
  }
}

template<int F, int MODE>
__global__ __launch_bounds__(256) void k_gather(const unsigned short* __restrict__ h,
                                                const float* __restrict__ dinv,
                                                const int* __restrict__ rowptr,
                                                const unsigned* __restrict__ rec,
                                                const unsigned short* __restrict__ add,
                                                unsigned short* __restrict__ outb,
                                                float* __restrict__ outf,
                                                const float* __restrict__ bias,
                                                unsigned short* __restrict__ c1) {
  gather_body<F, MODE>(blockIdx.x, h, dinv, rowptr, rec, add, outb, outf, bias, c1);
}

// ---- triple K=192 GEMM sharing A=c1: out(fp32,+bc) | z1(bf16) | z2(bf16) ----
__global__ __launch_bounds__(256) void k_mgemm3(const unsigned short* __restrict__ A,
                                                const unsigned short* __restrict__ BfWc,
                                                const float* __restrict__ bc,
                                                float* __restrict__ out,
                                                unsigned short* __restrict__ z1,
                                                unsigned short* __restrict__ z2) {
  constexpr int KT = 6;
  int lane = threadIdx.x & 63;
  int wave = blockIdx.x * 4 + (threadIdx.x >> 6);
  int r0 = wave * 16;
  if (r0 >= NN) return;
  int lrow = lane & 15, lgrp = lane >> 4;
  const unsigned short* ap = A + (size_t)(r0 + lrow) * 192 + lgrp * 8;
  const unsigned short* B0 = BfWc;
  const unsigned short* B1 = BfWc + (size_t)1536 * 8;
  const unsigned short* B2 = BfWc + (size_t)2 * 1536 * 8;
  f32x4 a0[4], a1[4], a2[4];
#pragma unroll
  for (int nt = 0; nt < 4; ++nt) {
    a0[nt] = (f32x4){0.f, 0.f, 0.f, 0.f};
    a1[nt] = (f32x4){0.f, 0.f, 0.f, 0.f};
    a2[nt] = (f32x4){0.f, 0.f, 0.f, 0.f};
  }
#pragma unroll
  for (int kt = 0; kt < KT; ++kt) {
    bf16x8 af = *reinterpret_cast<const bf16x8*>(ap + kt * 32);
#pragma unroll
    for (int nt = 0; nt < 4; ++nt) {
      size_t fo = (size_t)((kt * 4 + nt) * 64 + lane) * 8;
      bf16x8 b0 = *reinterpret_cast<const bf16x8*>(B0 + fo);
      bf16x8 b1 = *reinterpret_cast<const bf16x8*>(B1 + fo);
      bf16x8 b2 = *reinterpret_cast<const bf16x8*>(B2 + fo);
      a0[nt] = __builtin_amdgcn_mfma_f32_16x16x32_bf16(af, b0, a0[nt], 0, 0, 0);
      a1[nt] = __builtin_amdgcn_mfma_f32_16x16x32_bf16(af, b1, a1[nt], 0, 0, 0);
      a2[nt] = __builtin_amdgcn_mfma_f32_16x16x32_bf16(af, b2, a2[nt], 0, 0, 0);
    }
  }
#pragma unroll
  for (int nt = 0; nt < 4; ++nt) {
#pragma unroll
    for (int reg = 0; reg < 4; ++reg) {
      int rr = r0 + lgrp * 4 + reg;
      int cc = nt * 16 + lrow;
      out[(size_t)rr * 64 + cc] = a0[nt][reg] + bc[cc];
      z1[(size_t)rr * 64 + cc] = f2bf(a1[nt][reg]);
      z2[(size_t)rr * 64 + cc] = f2bf(a2[nt][reg]);
    }
  }
}

extern "C" void kernel_launch(void* const* d_in, const int* in_sizes, int n_in,
                              void* d_out, int out_size, void* d_ws, size_t ws_size,
                              hipStream_t stream) {
  const float* x    = (const float*)d_in[0];
  const int*   ei   = (const int*)d_in[1];
  const float* ew   = (const float*)d_in[2];
  const float* W1   = (const float*)d_in[3];
  const float* b1   = (const float*)d_in[4];
  const float* W2   = (const float*)d_in[5];
  const float* b2   = (const float*)d_in[6];
  const float* Wlin = (const float*)d_in[7];
  const float* bl   = (const float*)d_in[8];
  float* out = (float*)d_out;

  const int* row = ei;
  const int* col = ei + NE;

  char* wsb = (char*)d_ws;
  unsigned long long* packed8 = (unsigned long long*)wsb; wsb += (size_t)8 * NN * 8;
  float* dinv    = (float*)wsb;  wsb += NN * 4;
  int*   cnttot  = (int*)wsb;    wsb += NN * 4;
  int*   rowptr  = (int*)wsb;    wsb += (NN + 1) * 4;
  int*   partial = (int*)wsb;    wsb += 256 * 4;
  wsb = (char*)(((size_t)wsb + 15) & ~(size_t)15);
  unsigned short* cumoff = (unsigned short*)wsb; wsb += (size_t)NN * 8 * 2;
  unsigned short* posarr = (unsigned short*)wsb; wsb += NE * 2;
  wsb = (char*)(((size_t)wsb + 15) & ~(size_t)15);
  unsigned* rec  = (unsigned*)wsb; wsb += (size_t)NE * 4;
  float* Wc      = (float*)wsb;  wsb += 3 * 192 * 64 * 4;
  float* bc      = (float*)wsb;  wsb += 64 * 4;
  wsb = (char*)(((size_t)wsb + 15) & ~(size_t)15);
  unsigned short* BfW1 = (unsigned short*)wsb; wsb += (size_t)3 * 768 * 8 * 2;
  unsigned short* BfWc = (unsigned short*)wsb; wsb += (size_t)3 * 1536 * 8 * 2;
  wsb = (char*)(((size_t)wsb + 15) & ~(size_t)15);
  unsigned short* xb   = (unsigned short*)wsb; wsb += (size_t)NN * 96 * 2;
  unsigned short* c1   = (unsigned short*)wsb; wsb += (size_t)NN * 192 * 2;
  unsigned short* bufB = (unsigned short*)wsb;  // y(128)|q2(64), then z1|z2|sB (3*64)
  unsigned short* y  = bufB;
  unsigned short* q2 = bufB + (size_t)NN * 128;
  unsigned short* z1 = bufB;
  unsigned short* z2 = bufB + (size_t)NN * 64;
  unsigned short* sB = bufB + (size_t)NN * 128;

  // zero privatized histograms
  k_zero<<<ZB, 256, 0, stream>>>((uint4*)packed8);
  // mega-start: histogram atomics + weight prep + cast, one launch
  const int CASTB = (NN * 24 + 255) / 256;
  k_start<<<FB + 144 + 1 + 9 + CASTB, 256, 0, stream>>>(x, W1, W2, Wlin, b2, bl,
                                                        col, ew, packed8, posarr,
                                                        Wc, bc, BfW1, xb);
  // dinv + rowptr
  k_scan_part<<<NB, 256, 0, stream>>>(packed8, partial, dinv, cnttot, cumoff);
  k_scan_final<<<NB, 256, 0, stream>>>(cnttot, partial, rowptr);
  // CSR fill + BfWc pack + conv1 GEMM (bf16 xb -> c1_0, y), co-launched
  k_fill3<<<FB + 18 + GG, 256, 0, stream>>>(row, col, ew, dinv, rowptr, posarr, cumoff,
                                            rec, Wc, BfWc, xb, BfW1, b1, c1, y);

  // conv1 propagation: q = A y -> c1_1 (bias+relu) | q2; t = A q2 -> c1_2
  k_gather<128, 3><<<G128, 256, 0, stream>>>(y, dinv, rowptr, rec, nullptr, q2, nullptr,
                                             b1 + 64, c1);
  k_gather<64, 4><<<G64, 256, 0, stream>>>(q2, dinv, rowptr, rec, nullptr, nullptr, nullptr,
                                           b1 + 128, c1);

  // conv2 + final linear (re-associated): out = c1@Wc0 + bc + A(z1 + A z2)
  k_mgemm3<<<GG, 256, 0, stream>>>(c1, BfWc, bc, out, z1, z2);
  k_gather<64, 1><<<G64, 256, 0, stream>>>(z2, dinv, rowptr, rec, z1, sB, nullptr,
                                           nullptr, nullptr);
  k_gather<64, 2><<<G64, 256, 0, stream>>>(sB, dinv, rowptr, rec, nullptr, nullptr, out,
                                           nullptr, nullptr);
}